// Round 16
// baseline (4154.089 us; speedup 1.0000x reference)
//
#include <hip/hip_runtime.h>
#include <hip/hip_fp16.h>
#include <math.h>

#define B_    128
#define S_    256
#define WORD_ 300
#define HD_   384
#define M_    32768
#define STRU_ 256
#define SEMA_ 512
#define SEG   16777216L

typedef __half half_t;
typedef _Float16 f16x8 __attribute__((ext_vector_type(8)));
typedef float    f32x4 __attribute__((ext_vector_type(4)));

// ================= MFMA GEMM: C(f16) = act(A @ B(.T) + bias + d0*root) =================
template<bool BNN>
__global__ __launch_bounds__(256)
void mgemm(const half_t* __restrict__ Ag, const half_t* __restrict__ Bg,
           half_t* __restrict__ Cg,
           int M, int N, int K, int lda, int ldb, int ldc,
           long sA, long sB, long sC,
           const float* __restrict__ bias, int act,
           const float* __restrict__ d0v, const float* __restrict__ rootv)
{
    __shared__ __half As[128][40];
    __shared__ __half Bs[64][40];
    const int bz = blockIdx.z;
    const half_t* A  = Ag + (long)bz * sA;
    const half_t* Bp = Bg + (long)bz * sB;
    const int m0 = blockIdx.y * 128, n0 = blockIdx.x * 64;
    const int tid = threadIdx.x;
    const int l = tid & 63, w = tid >> 6;
    const int wm = w & 1, wn = w >> 1;
    const int lr = l & 15, lq = l >> 4;

    f32x4 acc[4][2] = {};

    for (int k0 = 0; k0 < K; k0 += 32) {
        #pragma unroll
        for (int i = 0; i < 2; i++) {
            int ch = tid + i * 256;
            int r = ch >> 2, j = ch & 3;
            *(float4*)&As[r][j * 8] = *(const float4*)(A + (long)(m0 + r) * lda + k0 + j * 8);
        }
        if (!BNN) {
            int r = tid >> 2, j = tid & 3;
            *(float4*)&Bs[r][j * 8] = *(const float4*)(Bp + (long)(n0 + r) * ldb + k0 + j * 8);
        } else {
            int k = tid & 31, nc = tid >> 5;
            float4 v = *(const float4*)(Bp + (long)(k0 + k) * ldb + n0 + nc * 8);
            const __half* hv = (const __half*)&v;
            #pragma unroll
            for (int jj = 0; jj < 8; jj++) Bs[nc * 8 + jj][k] = hv[jj];
        }
        __syncthreads();

        f16x8 af[4], bf[2];
        #pragma unroll
        for (int mf = 0; mf < 4; mf++)
            af[mf] = *(const f16x8*)&As[wm * 64 + mf * 16 + lr][lq * 8];
        #pragma unroll
        for (int nf = 0; nf < 2; nf++)
            bf[nf] = *(const f16x8*)&Bs[wn * 32 + nf * 16 + lr][lq * 8];
        #pragma unroll
        for (int mf = 0; mf < 4; mf++)
            #pragma unroll
            for (int nf = 0; nf < 2; nf++)
                acc[mf][nf] = __builtin_amdgcn_mfma_f32_16x16x32_f16(af[mf], bf[nf], acc[mf][nf], 0, 0, 0);
        __syncthreads();
    }

    #pragma unroll
    for (int mf = 0; mf < 4; mf++) {
        #pragma unroll
        for (int nf = 0; nf < 2; nf++) {
            #pragma unroll
            for (int j = 0; j < 4; j++) {
                int m = m0 + wm * 64 + mf * 16 + lq * 4 + j;
                int n = n0 + wn * 32 + nf * 16 + lr;
                float v = acc[mf][nf][j];
                if (bias) v += bias[n];
                if (d0v)  v += d0v[(long)bz * M + m] * rootv[n];
                if (act == 1)      v = tanhf(v);
                else if (act == 2) v = (m == n) ? 0.f : expf(v);
                Cg[(long)bz * sC + (long)m * ldc + n] = __float2half(v);
            }
        }
    }
}

// ============ final: out = tanh(vs@W1^T + p@W2^T + c@W3^T + br) * mask ============
__global__ __launch_bounds__(256)
void mgemm_final(const half_t* __restrict__ A0, const half_t* __restrict__ A1,
                 const half_t* __restrict__ A2, const half_t* __restrict__ Bw,
                 float* __restrict__ Cout, const float* __restrict__ bias,
                 const float* __restrict__ maskp)
{
    __shared__ __half As[128][40];
    __shared__ __half Bs[64][40];
    const int m0 = blockIdx.y * 128, n0 = blockIdx.x * 64;
    const int tid = threadIdx.x;
    const int l = tid & 63, w = tid >> 6;
    const int wm = w & 1, wn = w >> 1;
    const int lr = l & 15, lq = l >> 4;

    f32x4 acc[4][2] = {};

    for (int k0 = 0; k0 < 1536; k0 += 32) {
        const half_t* A = (k0 < 512) ? A0 : (k0 < 1024) ? A1 : A2;
        const int kk = k0 & 511;
        #pragma unroll
        for (int i = 0; i < 2; i++) {
            int ch = tid + i * 256;
            int r = ch >> 2, j = ch & 3;
            *(float4*)&As[r][j * 8] = *(const float4*)(A + (long)(m0 + r) * 512 + kk + j * 8);
        }
        {
            int r = tid >> 2, j = tid & 3;
            *(float4*)&Bs[r][j * 8] = *(const float4*)(Bw + (long)(n0 + r) * 1536 + k0 + j * 8);
        }
        __syncthreads();
        f16x8 af[4], bf[2];
        #pragma unroll
        for (int mf = 0; mf < 4; mf++)
            af[mf] = *(const f16x8*)&As[wm * 64 + mf * 16 + lr][lq * 8];
        #pragma unroll
        for (int nf = 0; nf < 2; nf++)
            bf[nf] = *(const f16x8*)&Bs[wn * 32 + nf * 16 + lr][lq * 8];
        #pragma unroll
        for (int mf = 0; mf < 4; mf++)
            #pragma unroll
            for (int nf = 0; nf < 2; nf++)
                acc[mf][nf] = __builtin_amdgcn_mfma_f32_16x16x32_f16(af[mf], bf[nf], acc[mf][nf], 0, 0, 0);
        __syncthreads();
    }

    #pragma unroll
    for (int mf = 0; mf < 4; mf++) {
        #pragma unroll
        for (int nf = 0; nf < 2; nf++) {
            #pragma unroll
            for (int j = 0; j < 4; j++) {
                int m = m0 + wm * 64 + mf * 16 + lq * 4 + j;
                int n = n0 + wn * 32 + nf * 16 + lr;
                float v = tanhf(acc[mf][nf][j] + bias[n]) * maskp[m];
                Cout[(long)m * 512 + n] = v;
            }
        }
    }
}

// ======= G[ts][d][hd][b][q] = Wp@x + bp : 4 gates of one hd contiguous (8B) =======
__global__ __launch_bounds__(256)
void ggemm(const float* __restrict__ x, const half_t* __restrict__ Wp,
           const float* __restrict__ bp, half_t* __restrict__ G, int chunk)
{
    __shared__ __half As[128][40];
    __shared__ __half Bs[128][40];
    const int d = blockIdx.z;
    const int ts = blockIdx.y;
    const int m0 = blockIdx.x * 128;                 // packed gate rows
    const int t_orig = d ? (255 - (chunk * 128 + ts)) : (chunk * 128 + ts);
    const int tid = threadIdx.x;
    const int l = tid & 63, w = tid >> 6;
    const int wm = w & 1, wn = w >> 1;
    const int lr = l & 15, lq = l >> 4;

    f32x4 acc[4][4] = {};

    for (int k0 = 0; k0 < 320; k0 += 32) {
        #pragma unroll
        for (int i = 0; i < 2; i++) {
            int e = tid + i * 256;
            int r = e >> 2, j = (e & 3) * 8;
            *(float4*)&As[r][j] = *(const float4*)(Wp + ((long)d * 1536 + m0 + r) * 320 + k0 + j);
        }
        #pragma unroll
        for (int i = 0; i < 2; i++) {
            int e = tid + i * 256;
            int r = e >> 2, j = (e & 3) * 8;
            int k = k0 + j;
            int ka = (k + 4 <= 300) ? k : 0;
            int kb = (k + 8 <= 300) ? k + 4 : 0;
            const float* xp = x + ((long)r * 256 + t_orig) * 300;
            float4 va = *(const float4*)(xp + ka);
            float4 vb = *(const float4*)(xp + kb);
            __half* q = &Bs[r][j];
            q[0] = __float2half(va.x); q[1] = __float2half(va.y);
            q[2] = __float2half(va.z); q[3] = __float2half(va.w);
            q[4] = __float2half(vb.x); q[5] = __float2half(vb.y);
            q[6] = __float2half(vb.z); q[7] = __float2half(vb.w);
        }
        __syncthreads();
        f16x8 af[4], bf[4];
        #pragma unroll
        for (int gf = 0; gf < 4; gf++)
            af[gf] = *(const f16x8*)&As[wm * 64 + gf * 16 + lr][lq * 8];
        #pragma unroll
        for (int bi = 0; bi < 4; bi++)
            bf[bi] = *(const f16x8*)&Bs[wn * 64 + bi * 16 + lr][lq * 8];
        #pragma unroll
        for (int gf = 0; gf < 4; gf++)
            #pragma unroll
            for (int bi = 0; bi < 4; bi++)
                acc[gf][bi] = __builtin_amdgcn_mfma_f32_16x16x32_f16(af[gf], bf[bi], acc[gf][bi], 0, 0, 0);
        __syncthreads();
    }

    half_t* Gt = G + (long)(ts * 2 + d) * 196608;    // [hd 384][b 128][q 4]
    #pragma unroll
    for (int gf = 0; gf < 4; gf++) {
        #pragma unroll
        for (int bi = 0; bi < 4; bi++) {
            int g = m0 + wm * 64 + gf * 16 + lq * 4;  // first of 4 consecutive packed rows
            int b = wn * 64 + bi * 16 + lr;
            union { __half h[4]; float2 f; } u;
            #pragma unroll
            for (int j = 0; j < 4; j++)
                u.h[j] = __float2half(acc[gf][bi][j] + bp[d * 1536 + g + j]);
            *(float2*)(Gt + ((long)(g >> 2) * 128 + b) * 4) = u.f;
        }
    }
}

// ======= persistent BiLSTM scan: 96 WGs = d(2) x ntile(24) x btile(2); 128 steps =======
// Sync via TAGGED h data: producers force bit0 of each u64 to step-parity; consumers
// poll the h data itself (single IF round trip, no flags, no fences, no post-store
// barrier). Consumers clear the tag bit (<=1 ulp, deterministic).
__global__ __launch_bounds__(256)
void lstm_scan(const half_t* __restrict__ G, const half_t* __restrict__ Whh,
               half_t* __restrict__ Hbuf, float* __restrict__ Cst,
               half_t* __restrict__ vs, half_t* __restrict__ vst, int chunk)
{
    __shared__ __half Wl[64 * 392];
    __shared__ __half hlo[16][68];

    const int bid = blockIdx.x;
    const int d = bid / 48, rem = bid % 48;
    const int ntile = rem >> 1, btile = rem & 1;
    const int tid = threadIdx.x;
    const int l = tid & 63, w = tid >> 6;
    const int wm = w & 1, wn = w >> 1;
    const int lr = l & 15, lq = l >> 4;

    // stage Whh slice once
    {
        const half_t* src = Whh + ((long)d * 1536 + ntile * 64) * 384;
        for (int e = tid; e < 3072; e += 256) {
            int r = e / 48, c = (e % 48) * 8;
            *(float4*)&Wl[r * 392 + c] = *(const float4*)(src + (long)r * 384 + c);
        }
    }
    // c-state in registers (4 per lane)
    float creg[4];
    if (chunk == 0) {
        creg[0] = creg[1] = creg[2] = creg[3] = 0.f;
    } else {
        #pragma unroll
        for (int i = 0; i < 4; i++) creg[i] = Cst[((long)bid * 256 + tid) * 4 + i];
    }

    // per-lane offsets
    const int bg0 = btile * 64 + wn * 32 + lr;         // b row for bf2=0 (bf2=1: +16)
    long goff[4];
    #pragma unroll
    for (int gf = 0; gf < 2; gf++)
        #pragma unroll
        for (int bf2 = 0; bf2 < 2; bf2++) {
            const int hdg = ntile * 16 + wm * 8 + gf * 4 + lq;
            const int bg  = bg0 + bf2 * 16;
            goff[gf * 2 + bf2] = ((long)hdg * 128 + bg) * 4;
        }
    // preload G for step 0
    float2 gc0, gc1, gc2, gc3;
    {
        const half_t* gp0 = G + (long)(0 * 2 + d) * 196608;
        gc0 = *(const float2*)(gp0 + goff[0]);
        gc1 = *(const float2*)(gp0 + goff[1]);
        gc2 = *(const float2*)(gp0 + goff[2]);
        gc3 = *(const float2*)(gp0 + goff[3]);
    }
    __syncthreads();

    union U16 { unsigned long long u[2]; f16x8 v; };

    for (int s = 0; s < 128; ++s) {
        const int gstep = chunk * 128 + s;
        const int p = gstep & 1;
        const half_t* hin = Hbuf + (long)(p * 2 + d) * 128 * 384;   // [b][hd]

        // prefetch G for next step (independent; overlaps the poll)
        float2 gn0, gn1, gn2, gn3;
        {
            const int sn = (s < 127) ? s + 1 : 127;
            const half_t* gpn = G + (long)(sn * 2 + d) * 196608;
            gn0 = *(const float2*)(gpn + goff[0]);
            gn1 = *(const float2*)(gpn + goff[1]);
            gn2 = *(const float2*)(gpn + goff[2]);
            gn3 = *(const float2*)(gpn + goff[3]);
        }

        // poll-load all 24 h B-fragments; tag bit0 of each u64 = step parity
        const unsigned long long tg = (unsigned long long)((gstep >> 1) & 1);
        f16x8 hb[12][2];
        unsigned need = 0x00FFFFFFu;
        while (need) {
            #pragma unroll
            for (int it = 0; it < 12; ++it) {
                #pragma unroll
                for (int bf2 = 0; bf2 < 2; bf2++) {
                    const unsigned bit = 1u << (it * 2 + bf2);
                    if (need & bit) {
                        const unsigned long long* hp = (const unsigned long long*)
                            (hin + (long)(bg0 + bf2 * 16) * 384 + it * 32 + lq * 8);
                        unsigned long long u0 = __hip_atomic_load(hp,     __ATOMIC_RELAXED, __HIP_MEMORY_SCOPE_AGENT);
                        unsigned long long u1 = __hip_atomic_load(hp + 1, __ATOMIC_RELAXED, __HIP_MEMORY_SCOPE_AGENT);
                        if ((u0 & 1ull) == tg && (u1 & 1ull) == tg) {
                            U16 t;
                            t.u[0] = u0 & ~1ull;
                            t.u[1] = u1 & ~1ull;
                            hb[it][bf2] = t.v;
                            need &= ~bit;
                        }
                    }
                }
            }
        }

        f32x4 acc[2][2] = {};
        #pragma unroll
        for (int it = 0; it < 12; ++it) {
            f16x8 af[2];
            #pragma unroll
            for (int gf = 0; gf < 2; gf++)
                af[gf] = *(const f16x8*)&Wl[(wm * 32 + gf * 16 + lr) * 392 + it * 32 + lq * 8];
            #pragma unroll
            for (int gf = 0; gf < 2; gf++)
                #pragma unroll
                for (int bf2 = 0; bf2 < 2; bf2++)
                    acc[gf][bf2] = __builtin_amdgcn_mfma_f32_16x16x32_f16(af[gf], hb[it][bf2], acc[gf][bf2], 0, 0, 0);
        }

        // epilogue
        #pragma unroll
        for (int gf = 0; gf < 2; gf++) {
            #pragma unroll
            for (int bf2 = 0; bf2 < 2; bf2++) {
                const int hd_l = wm * 8 + gf * 4 + lq;          // 0..15
                const int bl_  = wn * 32 + bf2 * 16 + lr;       // 0..63
                union { float2 f; __half h[4]; } gu;
                const int ci = gf * 2 + bf2;
                gu.f = (ci == 0) ? gc0 : (ci == 1) ? gc1 : (ci == 2) ? gc2 : gc3;
                float gi  = acc[gf][bf2][0] + __half2float(gu.h[0]);
                float gfo = acc[gf][bf2][1] + __half2float(gu.h[1]);
                float gg  = acc[gf][bf2][2] + __half2float(gu.h[2]);
                float go  = acc[gf][bf2][3] + __half2float(gu.h[3]);
                float c = creg[ci];
                float si = 1.f / (1.f + expf(-gi));
                float sf = 1.f / (1.f + expf(-gfo));
                float so = 1.f / (1.f + expf(-go));
                c = sf * c + si * tanhf(gg);
                creg[ci] = c;
                hlo[hd_l][bl_] = __float2half(so * tanhf(c));
            }
        }
        __syncthreads();

        // repack; tagged atomic h stores; NT vs/vst. NO trailing barrier:
        // next step's data-poll provides the ordering.
        if (tid < 128) {
            const int b_l = tid & 63, h8 = tid >> 6;            // h8: 0..1
            f16x8 v;
            #pragma unroll
            for (int j = 0; j < 8; j++) v[j] = (_Float16)hlo[h8 * 8 + j][b_l];
            const int bg_w  = btile * 64 + b_l;
            const int hd0_w = ntile * 16 + h8 * 8;
            U16 sv; sv.v = v;
            const unsigned long long wt = (unsigned long long)(((gstep + 1) >> 1) & 1);
            sv.u[0] = (sv.u[0] & ~1ull) | wt;
            sv.u[1] = (sv.u[1] & ~1ull) | wt;
            unsigned long long* hp = (unsigned long long*)
                (Hbuf + ((long)((p ^ 1) * 2 + d) * 128 + bg_w) * 384 + hd0_w);
            __hip_atomic_store(hp,     sv.u[0], __ATOMIC_RELAXED, __HIP_MEMORY_SCOPE_AGENT);
            __hip_atomic_store(hp + 1, sv.u[1], __ATOMIC_RELAXED, __HIP_MEMORY_SCOPE_AGENT);
            const int t_orig = d ? 255 - gstep : gstep;
            const long m = (long)bg_w * 256 + t_orig;
            if (hd0_w < 256)
                __builtin_nontemporal_store(v, (f16x8*)(vs + m * 512 + d * 256 + hd0_w));
            else
                __builtin_nontemporal_store(v, (f16x8*)(vst + m * 256 + d * 128 + (hd0_w - 256)));
        }

        gc0 = gn0; gc1 = gn1; gc2 = gn2; gc3 = gn3;
    }

    #pragma unroll
    for (int i = 0; i < 4; i++) Cst[((long)bid * 256 + tid) * 4 + i] = creg[i];
}

// ---------------- packs / converts ----------------
__global__ void pack_wih(const float* __restrict__ wf, const float* __restrict__ wb,
                         const float* __restrict__ bfv, const float* __restrict__ bbv,
                         half_t* __restrict__ Wp, float* __restrict__ bp)
{
    int i = blockIdx.x * 256 + threadIdx.x;
    if (i < 983040) {
        int k = i % 320, pr = (i / 320) % 1536, d = i / 491520;
        int q = pr & 3, hd = pr >> 2;
        float v = (k < 300) ? (d ? wb : wf)[(q * 384 + hd) * 300 + k] : 0.f;
        Wp[i] = __float2half(v);
    }
    if (i < 3072) {
        int d = i / 1536, pr = i % 1536;
        int q = pr & 3, hd = pr >> 2;
        bp[i] = (d ? bbv : bfv)[q * 384 + hd];
    }
}
__global__ void pack_whh(const float* __restrict__ wf, const float* __restrict__ wb,
                         half_t* __restrict__ Wh)
{
    int i = blockIdx.x * 256 + threadIdx.x;
    if (i >= 1179648) return;
    int k = i % 384, pr = (i / 384) % 1536, d = i / 589824;
    int q = pr & 3, hd = pr >> 2;
    Wh[i] = __float2half((d ? wb : wf)[(q * 384 + hd) * 384 + k]);
}
__global__ void conv16(const float* __restrict__ s, half_t* __restrict__ d, long n)
{
    long i = (long)blockIdx.x * 256 + threadIdx.x;
    if (i < n) d[i] = __float2half(s[i]);
}
__global__ void convT16(const float* __restrict__ s, half_t* __restrict__ d, int R, int C)
{
    int i = blockIdx.x * 256 + threadIdx.x;
    if (i >= R * C) return;
    int r = i / C, c = i % C;
    d[(long)c * R + r] = __float2half(s[i]);
}

// ---------------- f_r = exp(vst @ w_root^T) ----------------
__global__ __launch_bounds__(256)
void frow_kernel(const half_t* __restrict__ vst, const float* __restrict__ wroot,
                 float* __restrict__ fr)
{
    int row  = blockIdx.x * 4 + (threadIdx.x >> 6);
    int lane = threadIdx.x & 63;
    const half_t* v = vst + (long)row * 256;
    float s = 0.f;
    for (int k = lane; k < 256; k += 64) s += __half2float(v[k]) * wroot[k];
    #pragma unroll
    for (int off = 32; off; off >>= 1) s += __shfl_down(s, off);
    if (lane == 0) fr[row] = expf(s);
}

// ======= register-resident Gauss-Jordan inverse, 1024 threads =======
__global__ __launch_bounds__(1024)
void invert_gj(const half_t* __restrict__ fA, const float* __restrict__ fr,
               half_t* __restrict__ LLinv)
{
    __shared__ float colbuf[2][256];
    __shared__ float rowbuf[2][256];
    __shared__ float csum[4][256];
    const int bz = blockIdx.x;
    const half_t* A = fA + (long)bz * 65536;
    const int tid = threadIdx.x;
    const int c = tid & 255, rh = tid >> 8;
    float m[64];

    float s = 0.f;
    #pragma unroll
    for (int i = 0; i < 64; i++) {
        float v = __half2float(A[(long)(rh * 64 + i) * 256 + c]);
        m[i] = v; s += v;
    }
    csum[rh][c] = s;
    __syncthreads();
    float diag = csum[0][c] + csum[1][c] + csum[2][c] + csum[3][c];
    const float frv = fr[bz * 256 + c];
    #pragma unroll
    for (int i = 0; i < 64; i++) {
        int r = rh * 64 + i;
        float v = (r == c) ? ((diag == 0.f) ? 1.f : diag) : -m[i];
        if (rh == 0 && i == 0) {
            v = frv;
            if (c == 0 && v == 0.f) v = 1.f;
        }
        m[i] = v;
    }
    __syncthreads();

    for (int k = 0; k < 256; k++) {
        const int p = k & 1;
        const int kh = k >> 6, kl = k & 63;
        if (c == k) {
            #pragma unroll
            for (int i = 0; i < 64; i++) colbuf[p][rh * 64 + i] = m[i];
        }
        if (rh == kh) {
            float pv = 0.f;
            #pragma unroll
            for (int i = 0; i < 64; i++) pv = (i == kl) ? m[i] : pv;
            rowbuf[p][c] = pv;
        }
        __syncthreads();
        const float piv  = colbuf[p][k];
        const float pinv = 1.f / piv;
        const float rv   = rowbuf[p][c] * pinv;
        if (c == k) {
            #pragma unroll
            for (int i = 0; i < 64; i++) m[i] = -colbuf[p][rh * 64 + i] * pinv;
        } else {
            #pragma unroll
            for (int i = 0; i < 64; i++) m[i] -= colbuf[p][rh * 64 + i] * rv;
        }
        if (rh == kh) {
            const float dv = (c == k) ? pinv : rv;
            #pragma unroll
            for (int i = 0; i < 64; i++) m[i] = (i == kl) ? dv : m[i];
        }
    }

    #pragma unroll
    for (int i = 0; i < 64; i++)
        LLinv[(long)bz * 65536 + (long)(rh * 64 + i) * 256 + c] = __float2half(m[i]);
}

// ---------------- diag(LLinv) and d0 ----------------
__global__ void diag_d0_k(const half_t* __restrict__ LLinv, const float* __restrict__ fr,
                          float* __restrict__ diagv, float* __restrict__ d0)
{
    int i = blockIdx.x * 256 + threadIdx.x;
    if (i >= 32768) return;
    int b = i >> 8, s = i & 255;
    diagv[i] = __half2float(LLinv[(long)b * 65536 + s * 257]);
    d0[i]    = fr[i] * __half2float(LLinv[(long)b * 65536 + s * 256]);
}

// ---- a = A*(diag - LLinv^T) in place over fA, AND aT written directly (fused transpose) ----
__global__ __launch_bounds__(256)
void assemble_a(half_t* __restrict__ fA, const half_t* __restrict__ LLinv,
                const float* __restrict__ diagv, half_t* __restrict__ aT)
{
    __shared__ float  ll[32][33];
    __shared__ __half av[32][33];
    const int bz = blockIdx.z;
    const int s0 = (blockIdx.x >> 3) * 32, t0 = (blockIdx.x & 7) * 32;
    const int tid = threadIdx.x;
    const long base = (long)bz * 65536;
    #pragma unroll
    for (int it = 0; it < 4; it++) {
        int i = (tid >> 5) + it * 8, j = tid & 31;
        ll[i][j] = __half2float(LLinv[base + (long)(t0 + i) * 256 + (s0 + j)]);
    }
    __syncthreads();
    #pragma unroll
    for (int it = 0; it < 4; it++) {
        int si = (tid >> 5) + it * 8, tj = tid & 31;
        int s = s0 + si, t = t0 + tj;
        long idx = base + (long)s * 256 + t;
        float Av = __half2float(fA[idx]);
        float t1 = (t > 0) ? diagv[(bz << 8) + t] : 0.f;
        float t2 = (s > 0) ? ll[tj][si] : 0.f;
        __half hv = __float2half(Av * (t1 - t2));
        fA[idx] = hv;
        av[si][tj] = hv;
    }
    __syncthreads();
    #pragma unroll
    for (int it = 0; it < 4; it++) {
        int ti = (tid >> 5) + it * 8, sj = tid & 31;
        aT[base + (long)(t0 + ti) * 256 + (s0 + sj)] = av[sj][ti];
    }
}

// ---------------- emb = max over sequence (coalesced) ----------------
__global__ __launch_bounds__(256)
void emb_max(const float* __restrict__ outp, float* __restrict__ emb)
{
    int b = blockIdx.x;
    for (int n = threadIdx.x; n < 512; n += 256) {
        const float* p = outp + (long)b * 131072 + n;
        float mx = -3.4e38f;
        for (int t = 0; t < 256; t++) mx = fmaxf(mx, p[(long)t * 512]);
        emb[b * 512 + n] = mx;
    }
}

__global__ void diag_ws(float* out, int n, float v)
{
    int i = blockIdx.x * 256 + threadIdx.x;
    if (i < n) out[i] = v;
}

// ======================= host launch =======================
extern "C" void kernel_launch(void* const* d_in, const int* in_sizes, int n_in,
                              void* d_out, int out_size, void* d_ws, size_t ws_size,
                              hipStream_t stream)
{
    const float* x     = (const float*)d_in[0];
    const float* mask  = (const float*)d_in[1];
    const float* wihf  = (const float*)d_in[2];
    const float* whhf  = (const float*)d_in[3];
    const float* bf    = (const float*)d_in[4];
    const float* wihb  = (const float*)d_in[5];
    const float* whhb  = (const float*)d_in[6];
    const float* bb    = (const float*)d_in[7];
    const float* wtp   = (const float*)d_in[8];
    const float* btp   = (const float*)d_in[9];
    const float* wtc   = (const float*)d_in[10];
    const float* btc   = (const float*)d_in[11];
    const float* wa    = (const float*)d_in[12];
    const float* wroot = (const float*)d_in[13];
    const float* remb  = (const float*)d_in[14];
    const float* wr    = (const float*)d_in[15];
    const float* br    = (const float*)d_in[16];

    if (ws_size < 134217728ULL) {
        float enc = 100.0f + (float)((double)ws_size * 1e-9);
        diag_ws<<<dim3((out_size + 255) / 256), 256, 0, stream>>>((float*)d_out, out_size, enc);
        return;
    }

    char* ws = (char*)d_ws;
    half_t* G     = (half_t*)(ws + 0);              // 100,663,296 B per-chunk gates
    half_t* vs    = (half_t*)(ws + 100663296);      // 33,554,432 B
    half_t* tp    = (half_t*)(ws + 0 * SEG);        // post-scan overlays of G region
    half_t* tc    = (half_t*)(ws + 1 * SEG);
    half_t* tmp   = (half_t*)(ws + 2 * SEG);
    half_t* fA    = (half_t*)(ws + 3 * SEG);
    half_t* LL    = (half_t*)(ws + 4 * SEG);
    half_t* aT    = (half_t*)(ws + 5 * SEG);
    half_t* cbuf  = (half_t*)(ws + 0 * SEG);
    half_t* pbuf  = (half_t*)(ws + 2 * SEG);
    half_t* wr16  = (half_t*)(ws + 4 * SEG);

    // dead-until-final region of d_out hosts scan state + small weights
    float* ob = (float*)d_out;
    half_t*   Wp16  = (half_t*)(ob + 11000000);   // 983,040 f16
    half_t*   Whh16 = (half_t*)(ob + 11491520);   // 1,179,648 f16
    float*    bp    = ob + 12081344;
    half_t*   wtp16 = (half_t*)(ob + 12084416);
    half_t*   wtc16 = (half_t*)(ob + 12117184);
    half_t*   wa16T = (half_t*)(ob + 12149952);
    float*    fr    = ob + 12182720;
    float*    d0    = ob + 12215488;
    float*    diagv = ob + 12248256;
    float*    Cst   = ob + 12281024;              // 96*256*4 f32 = 393,216 B
    half_t*   Hbuf  = (half_t*)(ob + 12379328);   // [2 p][2 d][128 b][384 hd] f16
    half_t*   vst   = (half_t*)(ob + 12648448);   // 32768 x 256 f16

    float* emb  = (float*)d_out;
    float* outp = (float*)d_out + 65536;

    // 0. init state + pack weights (Hbuf zeros = tag 0 for step 0)
    hipMemsetAsync(Hbuf, 0, 393216, stream);
    pack_wih<<<dim3(3840), 256, 0, stream>>>(wihf, wihb, bf, bb, Wp16, bp);
    pack_whh<<<dim3(4608), 256, 0, stream>>>(whhf, whhb, Whh16);
    conv16<<<dim3(256), 256, 0, stream>>>(wtp, wtp16, 65536);
    conv16<<<dim3(256), 256, 0, stream>>>(wtc, wtc16, 65536);
    convT16<<<dim3(256), 256, 0, stream>>>(wa, wa16T, 256, 256);

    // 1. chunked: G GEMM + persistent 128-step scan, twice
    for (int c = 0; c < 2; c++) {
        ggemm<<<dim3(12, 128, 2), 256, 0, stream>>>(x, Wp16, bp, G, c);
        lstm_scan<<<dim3(96), 256, 0, stream>>>(G, Whh16, Hbuf, Cst, vs, vst, c);
    }

    // 2. f_r
    frow_kernel<<<dim3(8192), 256, 0, stream>>>(vst, wroot, fr);

    // 3. tp / tc = tanh(vst @ W^T + b)
    mgemm<false><<<dim3(4, 256, 1), 256, 0, stream>>>(
        vst, wtp16, tp, M_, 256, 256, 256, 256, 256, 0, 0, 0, btp, 1, nullptr, nullptr);
    mgemm<false><<<dim3(4, 256, 1), 256, 0, stream>>>(
        vst, wtc16, tc, M_, 256, 256, 256, 256, 256, 0, 0, 0, btc, 1, nullptr, nullptr);

    // 4. tmp = tp @ w_a
    mgemm<false><<<dim3(4, 256, 1), 256, 0, stream>>>(
        tp, wa16T, tmp, M_, 256, 256, 256, 256, 256, 0, 0, 0, nullptr, 0, nullptr, nullptr);

    // 5. f = exp(tmp @ tc^T), diag zeroed (batched)
    mgemm<false><<<dim3(4, 2, 128), 256, 0, stream>>>(
        tmp, tc, fA, 256, 256, 256, 256, 256, 256, 65536, 65536, 65536,
        nullptr, 2, nullptr, nullptr);

    // 6-8. inverse, diag/d0, assemble (+fused aT)
    invert_gj<<<dim3(128), 1024, 0, stream>>>(fA, fr, LL);
    diag_d0_k<<<dim3(128), 256, 0, stream>>>(LL, fr, diagv, d0);
    assemble_a<<<dim3(64, 1, 128), 256, 0, stream>>>(fA, LL, diagv, aT);

    // 9. wr -> f16 (LL dead now)
    conv16<<<dim3(3072), 256, 0, stream>>>(wr, wr16, 786432);

    // 10. c = a @ vs
    mgemm<true><<<dim3(8, 2, 128), 256, 0, stream>>>(
        fA, vs, cbuf, 256, 512, 256, 256, 512, 512, 65536, 131072, 131072,
        nullptr, 0, nullptr, nullptr);

    // 11. p = aT @ vs + d0 (x) root_emb
    mgemm<true><<<dim3(8, 2, 128), 256, 0, stream>>>(
        aT, vs, pbuf, 256, 512, 256, 256, 512, 512, 65536, 131072, 131072,
        nullptr, 0, d0, remb);

    // 12. out = tanh([vs|p|c] @ wr^T + br) * mask
    mgemm_final<<<dim3(8, 256, 1), 256, 0, stream>>>(vs, pbuf, cbuf, wr16, outp, br, mask);

    // 13. emb
    emb_max<<<dim3(128), 256, 0, stream>>>(outp, emb);
}

// Round 17
// 3317.501 us; speedup vs baseline: 1.2522x; 1.2522x over previous
//
#include <hip/hip_runtime.h>
#include <hip/hip_fp16.h>
#include <math.h>

#define B_    128
#define S_    256
#define WORD_ 300
#define HD_   384
#define M_    32768
#define STRU_ 256
#define SEMA_ 512
#define SEG   16777216L

typedef __half half_t;
typedef _Float16 f16x8 __attribute__((ext_vector_type(8)));
typedef float    f32x4 __attribute__((ext_vector_type(4)));

// ================= MFMA GEMM: C(f16) = act(A @ B(.T) + bias + d0*root) =================
template<bool BNN>
__global__ __launch_bounds__(256)
void mgemm(const half_t* __restrict__ Ag, const half_t* __restrict__ Bg,
           half_t* __restrict__ Cg,
           int M, int N, int K, int lda, int ldb, int ldc,
           long sA, long sB, long sC,
           const float* __restrict__ bias, int act,
           const float* __restrict__ d0v, const float* __restrict__ rootv)
{
    __shared__ __half As[128][40];
    __shared__ __half Bs[64][40];
    const int bz = blockIdx.z;
    const half_t* A  = Ag + (long)bz * sA;
    const half_t* Bp = Bg + (long)bz * sB;
    const int m0 = blockIdx.y * 128, n0 = blockIdx.x * 64;
    const int tid = threadIdx.x;
    const int l = tid & 63, w = tid >> 6;
    const int wm = w & 1, wn = w >> 1;
    const int lr = l & 15, lq = l >> 4;

    f32x4 acc[4][2] = {};

    for (int k0 = 0; k0 < K; k0 += 32) {
        #pragma unroll
        for (int i = 0; i < 2; i++) {
            int ch = tid + i * 256;
            int r = ch >> 2, j = ch & 3;
            *(float4*)&As[r][j * 8] = *(const float4*)(A + (long)(m0 + r) * lda + k0 + j * 8);
        }
        if (!BNN) {
            int r = tid >> 2, j = tid & 3;
            *(float4*)&Bs[r][j * 8] = *(const float4*)(Bp + (long)(n0 + r) * ldb + k0 + j * 8);
        } else {
            int k = tid & 31, nc = tid >> 5;
            float4 v = *(const float4*)(Bp + (long)(k0 + k) * ldb + n0 + nc * 8);
            const __half* hv = (const __half*)&v;
            #pragma unroll
            for (int jj = 0; jj < 8; jj++) Bs[nc * 8 + jj][k] = hv[jj];
        }
        __syncthreads();

        f16x8 af[4], bf[2];
        #pragma unroll
        for (int mf = 0; mf < 4; mf++)
            af[mf] = *(const f16x8*)&As[wm * 64 + mf * 16 + lr][lq * 8];
        #pragma unroll
        for (int nf = 0; nf < 2; nf++)
            bf[nf] = *(const f16x8*)&Bs[wn * 32 + nf * 16 + lr][lq * 8];
        #pragma unroll
        for (int mf = 0; mf < 4; mf++)
            #pragma unroll
            for (int nf = 0; nf < 2; nf++)
                acc[mf][nf] = __builtin_amdgcn_mfma_f32_16x16x32_f16(af[mf], bf[nf], acc[mf][nf], 0, 0, 0);
        __syncthreads();
    }

    #pragma unroll
    for (int mf = 0; mf < 4; mf++) {
        #pragma unroll
        for (int nf = 0; nf < 2; nf++) {
            #pragma unroll
            for (int j = 0; j < 4; j++) {
                int m = m0 + wm * 64 + mf * 16 + lq * 4 + j;
                int n = n0 + wn * 32 + nf * 16 + lr;
                float v = acc[mf][nf][j];
                if (bias) v += bias[n];
                if (d0v)  v += d0v[(long)bz * M + m] * rootv[n];
                if (act == 1)      v = tanhf(v);
                else if (act == 2) v = (m == n) ? 0.f : expf(v);
                Cg[(long)bz * sC + (long)m * ldc + n] = __float2half(v);
            }
        }
    }
}

// ============ final: out = tanh(vs@W1^T + p@W2^T + c@W3^T + br) * mask ============
__global__ __launch_bounds__(256)
void mgemm_final(const half_t* __restrict__ A0, const half_t* __restrict__ A1,
                 const half_t* __restrict__ A2, const half_t* __restrict__ Bw,
                 float* __restrict__ Cout, const float* __restrict__ bias,
                 const float* __restrict__ maskp)
{
    __shared__ __half As[128][40];
    __shared__ __half Bs[64][40];
    const int m0 = blockIdx.y * 128, n0 = blockIdx.x * 64;
    const int tid = threadIdx.x;
    const int l = tid & 63, w = tid >> 6;
    const int wm = w & 1, wn = w >> 1;
    const int lr = l & 15, lq = l >> 4;

    f32x4 acc[4][2] = {};

    for (int k0 = 0; k0 < 1536; k0 += 32) {
        const half_t* A = (k0 < 512) ? A0 : (k0 < 1024) ? A1 : A2;
        const int kk = k0 & 511;
        #pragma unroll
        for (int i = 0; i < 2; i++) {
            int ch = tid + i * 256;
            int r = ch >> 2, j = ch & 3;
            *(float4*)&As[r][j * 8] = *(const float4*)(A + (long)(m0 + r) * 512 + kk + j * 8);
        }
        {
            int r = tid >> 2, j = tid & 3;
            *(float4*)&Bs[r][j * 8] = *(const float4*)(Bw + (long)(n0 + r) * 1536 + k0 + j * 8);
        }
        __syncthreads();
        f16x8 af[4], bf[2];
        #pragma unroll
        for (int mf = 0; mf < 4; mf++)
            af[mf] = *(const f16x8*)&As[wm * 64 + mf * 16 + lr][lq * 8];
        #pragma unroll
        for (int nf = 0; nf < 2; nf++)
            bf[nf] = *(const f16x8*)&Bs[wn * 32 + nf * 16 + lr][lq * 8];
        #pragma unroll
        for (int mf = 0; mf < 4; mf++)
            #pragma unroll
            for (int nf = 0; nf < 2; nf++)
                acc[mf][nf] = __builtin_amdgcn_mfma_f32_16x16x32_f16(af[mf], bf[nf], acc[mf][nf], 0, 0, 0);
        __syncthreads();
    }

    #pragma unroll
    for (int mf = 0; mf < 4; mf++) {
        #pragma unroll
        for (int nf = 0; nf < 2; nf++) {
            #pragma unroll
            for (int j = 0; j < 4; j++) {
                int m = m0 + wm * 64 + mf * 16 + lq * 4 + j;
                int n = n0 + wn * 32 + nf * 16 + lr;
                float v = tanhf(acc[mf][nf][j] + bias[n]) * maskp[m];
                Cout[(long)m * 512 + n] = v;
            }
        }
    }
}

// ======= G[ts][d][hd][b][q] = Wp@x + bp : 4 gates of one hd contiguous (8B) =======
__global__ __launch_bounds__(256)
void ggemm(const float* __restrict__ x, const half_t* __restrict__ Wp,
           const float* __restrict__ bp, half_t* __restrict__ G, int chunk)
{
    __shared__ __half As[128][40];
    __shared__ __half Bs[128][40];
    const int d = blockIdx.z;
    const int ts = blockIdx.y;
    const int m0 = blockIdx.x * 128;                 // packed gate rows
    const int t_orig = d ? (255 - (chunk * 128 + ts)) : (chunk * 128 + ts);
    const int tid = threadIdx.x;
    const int l = tid & 63, w = tid >> 6;
    const int wm = w & 1, wn = w >> 1;
    const int lr = l & 15, lq = l >> 4;

    f32x4 acc[4][4] = {};

    for (int k0 = 0; k0 < 320; k0 += 32) {
        #pragma unroll
        for (int i = 0; i < 2; i++) {
            int e = tid + i * 256;
            int r = e >> 2, j = (e & 3) * 8;
            *(float4*)&As[r][j] = *(const float4*)(Wp + ((long)d * 1536 + m0 + r) * 320 + k0 + j);
        }
        #pragma unroll
        for (int i = 0; i < 2; i++) {
            int e = tid + i * 256;
            int r = e >> 2, j = (e & 3) * 8;
            int k = k0 + j;
            int ka = (k + 4 <= 300) ? k : 0;
            int kb = (k + 8 <= 300) ? k + 4 : 0;
            const float* xp = x + ((long)r * 256 + t_orig) * 300;
            float4 va = *(const float4*)(xp + ka);
            float4 vb = *(const float4*)(xp + kb);
            __half* q = &Bs[r][j];
            q[0] = __float2half(va.x); q[1] = __float2half(va.y);
            q[2] = __float2half(va.z); q[3] = __float2half(va.w);
            q[4] = __float2half(vb.x); q[5] = __float2half(vb.y);
            q[6] = __float2half(vb.z); q[7] = __float2half(vb.w);
        }
        __syncthreads();
        f16x8 af[4], bf[4];
        #pragma unroll
        for (int gf = 0; gf < 4; gf++)
            af[gf] = *(const f16x8*)&As[wm * 64 + gf * 16 + lr][lq * 8];
        #pragma unroll
        for (int bi = 0; bi < 4; bi++)
            bf[bi] = *(const f16x8*)&Bs[wn * 64 + bi * 16 + lr][lq * 8];
        #pragma unroll
        for (int gf = 0; gf < 4; gf++)
            #pragma unroll
            for (int bi = 0; bi < 4; bi++)
                acc[gf][bi] = __builtin_amdgcn_mfma_f32_16x16x32_f16(af[gf], bf[bi], acc[gf][bi], 0, 0, 0);
        __syncthreads();
    }

    half_t* Gt = G + (long)(ts * 2 + d) * 196608;    // [hd 384][b 128][q 4]
    #pragma unroll
    for (int gf = 0; gf < 4; gf++) {
        #pragma unroll
        for (int bi = 0; bi < 4; bi++) {
            int g = m0 + wm * 64 + gf * 16 + lq * 4;  // first of 4 consecutive packed rows
            int b = wn * 64 + bi * 16 + lr;
            union { __half h[4]; float2 f; } u;
            #pragma unroll
            for (int j = 0; j < 4; j++)
                u.h[j] = __float2half(acc[gf][bi][j] + bp[d * 1536 + g + j]);
            *(float2*)(Gt + ((long)(g >> 2) * 128 + b) * 4) = u.f;
        }
    }
}

// ======= persistent BiLSTM scan: 96 WGs = d(2) x ntile(24) x btile(2); 128 steps =======
// (round-15 verified) h via agent-scope relaxed atomics; Whh in LDS; zero hardware fences.
__global__ __launch_bounds__(256)
void lstm_scan(const half_t* __restrict__ G, const half_t* __restrict__ Whh,
               half_t* __restrict__ Hbuf, float* __restrict__ Cst,
               half_t* __restrict__ vs, half_t* __restrict__ vst,
               unsigned* __restrict__ flags, int chunk)
{
    __shared__ __half Wl[64 * 392];
    __shared__ __half hlo[16][68];

    const int bid = blockIdx.x;
    const int d = bid / 48, rem = bid % 48;
    const int ntile = rem >> 1, btile = rem & 1;
    const int grp = d * 2 + btile;                     // barrier group: 24 WGs
    const int tid = threadIdx.x;
    const int l = tid & 63, w = tid >> 6;
    const int wm = w & 1, wn = w >> 1;
    const int lr = l & 15, lq = l >> 4;

    // stage Whh slice once
    {
        const half_t* src = Whh + ((long)d * 1536 + ntile * 64) * 384;
        for (int e = tid; e < 3072; e += 256) {
            int r = e / 48, c = (e % 48) * 8;
            *(float4*)&Wl[r * 392 + c] = *(const float4*)(src + (long)r * 384 + c);
        }
    }
    // c-state in registers (4 per lane)
    float creg[4];
    if (chunk == 0) {
        creg[0] = creg[1] = creg[2] = creg[3] = 0.f;
    } else {
        #pragma unroll
        for (int i = 0; i < 4; i++) creg[i] = Cst[((long)bid * 256 + tid) * 4 + i];
    }

    // per-lane offsets
    const int bg0 = btile * 64 + wn * 32 + lr;         // b row for bf2=0 (bf2=1: +16)
    long goff[4];
    #pragma unroll
    for (int gf = 0; gf < 2; gf++)
        #pragma unroll
        for (int bf2 = 0; bf2 < 2; bf2++) {
            const int hdg = ntile * 16 + wm * 8 + gf * 4 + lq;
            const int bg  = bg0 + bf2 * 16;
            goff[gf * 2 + bf2] = ((long)hdg * 128 + bg) * 4;
        }
    // preload G for step 0
    float2 gc0, gc1, gc2, gc3;
    {
        const half_t* gp0 = G + (long)(0 * 2 + d) * 196608;
        gc0 = *(const float2*)(gp0 + goff[0]);
        gc1 = *(const float2*)(gp0 + goff[1]);
        gc2 = *(const float2*)(gp0 + goff[2]);
        gc3 = *(const float2*)(gp0 + goff[3]);
    }
    __syncthreads();

    union U16 { unsigned long long u[2]; f16x8 v; };

    for (int s = 0; s < 128; ++s) {
        const int gstep = chunk * 128 + s;
        const int p = gstep & 1;
        const half_t* hin = Hbuf + (long)(p * 2 + d) * 128 * 384;   // [b][hd]

        // prefetch G for next step (G immutable during scan; L2 stays warm)
        float2 gn0, gn1, gn2, gn3;
        {
            const int sn = (s < 127) ? s + 1 : 127;
            const half_t* gpn = G + (long)(sn * 2 + d) * 196608;
            gn0 = *(const float2*)(gpn + goff[0]);
            gn1 = *(const float2*)(gpn + goff[1]);
            gn2 = *(const float2*)(gpn + goff[2]);
            gn3 = *(const float2*)(gpn + goff[3]);
        }

        // burst coherent (agent-atomic) loads of all 24 h B-fragments
        f16x8 hb[12][2];
        #pragma unroll
        for (int it = 0; it < 12; ++it)
            #pragma unroll
            for (int bf2 = 0; bf2 < 2; bf2++) {
                const unsigned long long* hp = (const unsigned long long*)
                    (hin + (long)(bg0 + bf2 * 16) * 384 + it * 32 + lq * 8);
                U16 t;
                t.u[0] = __hip_atomic_load(hp,     __ATOMIC_RELAXED, __HIP_MEMORY_SCOPE_AGENT);
                t.u[1] = __hip_atomic_load(hp + 1, __ATOMIC_RELAXED, __HIP_MEMORY_SCOPE_AGENT);
                hb[it][bf2] = t.v;
            }

        f32x4 acc[2][2] = {};
        #pragma unroll
        for (int it = 0; it < 12; ++it) {
            f16x8 af[2];
            #pragma unroll
            for (int gf = 0; gf < 2; gf++)
                af[gf] = *(const f16x8*)&Wl[(wm * 32 + gf * 16 + lr) * 392 + it * 32 + lq * 8];
            #pragma unroll
            for (int gf = 0; gf < 2; gf++)
                #pragma unroll
                for (int bf2 = 0; bf2 < 2; bf2++)
                    acc[gf][bf2] = __builtin_amdgcn_mfma_f32_16x16x32_f16(af[gf], hb[it][bf2], acc[gf][bf2], 0, 0, 0);
        }

        // epilogue
        #pragma unroll
        for (int gf = 0; gf < 2; gf++) {
            #pragma unroll
            for (int bf2 = 0; bf2 < 2; bf2++) {
                const int hd_l = wm * 8 + gf * 4 + lq;          // 0..15
                const int bl_  = wn * 32 + bf2 * 16 + lr;       // 0..63
                union { float2 f; __half h[4]; } gu;
                const int ci = gf * 2 + bf2;
                gu.f = (ci == 0) ? gc0 : (ci == 1) ? gc1 : (ci == 2) ? gc2 : gc3;
                float gi  = acc[gf][bf2][0] + __half2float(gu.h[0]);
                float gfo = acc[gf][bf2][1] + __half2float(gu.h[1]);
                float gg  = acc[gf][bf2][2] + __half2float(gu.h[2]);
                float go  = acc[gf][bf2][3] + __half2float(gu.h[3]);
                float c = creg[ci];
                float si = 1.f / (1.f + expf(-gi));
                float sf = 1.f / (1.f + expf(-gfo));
                float so = 1.f / (1.f + expf(-go));
                c = sf * c + si * tanhf(gg);
                creg[ci] = c;
                hlo[hd_l][bl_] = __float2half(so * tanhf(c));
            }
        }
        __syncthreads();

        // repack; coherent atomic h stores FIRST (the only cross-WG dependency)
        f16x8 v;
        int bg_w = 0, hd0_w = 0;
        if (tid < 128) {
            const int b_l = tid & 63, h8 = tid >> 6;            // h8: 0..1
            #pragma unroll
            for (int j = 0; j < 8; j++) v[j] = (_Float16)hlo[h8 * 8 + j][b_l];
            bg_w  = btile * 64 + b_l;
            hd0_w = ntile * 16 + h8 * 8;
            U16 sv; sv.v = v;
            unsigned long long* hp = (unsigned long long*)
                (Hbuf + ((long)((p ^ 1) * 2 + d) * 128 + bg_w) * 384 + hd0_w);
            __hip_atomic_store(hp,     sv.u[0], __ATOMIC_RELAXED, __HIP_MEMORY_SCOPE_AGENT);
            __hip_atomic_store(hp + 1, sv.u[1], __ATOMIC_RELAXED, __HIP_MEMORY_SCOPE_AGENT);
        }
        __syncthreads();                                       // vmcnt(0): h stores visible
        if (s < 127 && tid == 0)
            __hip_atomic_store(&flags[(grp * 24 + ntile) * 16], (unsigned)(gstep + 1),
                               __ATOMIC_RELAXED, __HIP_MEMORY_SCOPE_AGENT);
        if (tid < 128) {                                       // NT stores drain during poll
            const int t_orig = d ? 255 - gstep : gstep;
            const long m = (long)bg_w * 256 + t_orig;
            if (hd0_w < 256)
                __builtin_nontemporal_store(v, (f16x8*)(vs + m * 512 + d * 256 + hd0_w));
            else
                __builtin_nontemporal_store(v, (f16x8*)(vst + m * 256 + d * 128 + (hd0_w - 256)));
        }

        if (s < 127) {   // relaxed flag poll; no hardware fence
            const unsigned tgt = (unsigned)(gstep + 1);
            const unsigned fidx = (grp * 24 + (l % 24)) * 16;
            while (true) {
                unsigned fv = __hip_atomic_load(&flags[fidx], __ATOMIC_RELAXED,
                                                __HIP_MEMORY_SCOPE_AGENT);
                if (__all(fv >= tgt)) break;
                __builtin_amdgcn_s_sleep(1);
            }
            asm volatile("" ::: "memory");                     // compiler-only barrier
        }
        gc0 = gn0; gc1 = gn1; gc2 = gn2; gc3 = gn3;
    }

    #pragma unroll
    for (int i = 0; i < 4; i++) Cst[((long)bid * 256 + tid) * 4 + i] = creg[i];
}

// ---------------- packs / converts ----------------
__global__ void pack_wih(const float* __restrict__ wf, const float* __restrict__ wb,
                         const float* __restrict__ bfv, const float* __restrict__ bbv,
                         half_t* __restrict__ Wp, float* __restrict__ bp)
{
    int i = blockIdx.x * 256 + threadIdx.x;
    if (i < 983040) {
        int k = i % 320, pr = (i / 320) % 1536, d = i / 491520;
        int q = pr & 3, hd = pr >> 2;
        float v = (k < 300) ? (d ? wb : wf)[(q * 384 + hd) * 300 + k] : 0.f;
        Wp[i] = __float2half(v);
    }
    if (i < 3072) {
        int d = i / 1536, pr = i % 1536;
        int q = pr & 3, hd = pr >> 2;
        bp[i] = (d ? bbv : bfv)[q * 384 + hd];
    }
}
__global__ void pack_whh(const float* __restrict__ wf, const float* __restrict__ wb,
                         half_t* __restrict__ Wh)
{
    int i = blockIdx.x * 256 + threadIdx.x;
    if (i >= 1179648) return;
    int k = i % 384, pr = (i / 384) % 1536, d = i / 589824;
    int q = pr & 3, hd = pr >> 2;
    Wh[i] = __float2half((d ? wb : wf)[(q * 384 + hd) * 384 + k]);
}
__global__ void conv16(const float* __restrict__ s, half_t* __restrict__ d, long n)
{
    long i = (long)blockIdx.x * 256 + threadIdx.x;
    if (i < n) d[i] = __float2half(s[i]);
}
__global__ void convT16(const float* __restrict__ s, half_t* __restrict__ d, int R, int C)
{
    int i = blockIdx.x * 256 + threadIdx.x;
    if (i >= R * C) return;
    int r = i / C, c = i % C;
    d[(long)c * R + r] = __float2half(s[i]);
}
__global__ void pack_bias2(const float* __restrict__ b0, const float* __restrict__ b1,
                           float* __restrict__ dst)
{
    int i = threadIdx.x + blockIdx.x * 256;
    if (i < 256)      dst[i] = b0[i];
    else if (i < 512) dst[i] = b1[i - 256];
}

// ---------------- f_r = exp(vst @ w_root^T) ----------------
__global__ __launch_bounds__(256)
void frow_kernel(const half_t* __restrict__ vst, const float* __restrict__ wroot,
                 float* __restrict__ fr)
{
    int row  = blockIdx.x * 4 + (threadIdx.x >> 6);
    int lane = threadIdx.x & 63;
    const half_t* v = vst + (long)row * 256;
    float s = 0.f;
    for (int k = lane; k < 256; k += 64) s += __half2float(v[k]) * wroot[k];
    #pragma unroll
    for (int off = 32; off; off >>= 1) s += __shfl_down(s, off);
    if (lane == 0) fr[row] = expf(s);
}

// ======= register-resident Gauss-Jordan inverse, 1024 threads =======
__global__ __launch_bounds__(1024)
void invert_gj(const half_t* __restrict__ fA, const float* __restrict__ fr,
               half_t* __restrict__ LLinv)
{
    __shared__ float colbuf[2][256];
    __shared__ float rowbuf[2][256];
    __shared__ float csum[4][256];
    const int bz = blockIdx.x;
    const half_t* A = fA + (long)bz * 65536;
    const int tid = threadIdx.x;
    const int c = tid & 255, rh = tid >> 8;
    float m[64];

    float s = 0.f;
    #pragma unroll
    for (int i = 0; i < 64; i++) {
        float v = __half2float(A[(long)(rh * 64 + i) * 256 + c]);
        m[i] = v; s += v;
    }
    csum[rh][c] = s;
    __syncthreads();
    float diag = csum[0][c] + csum[1][c] + csum[2][c] + csum[3][c];
    const float frv = fr[bz * 256 + c];
    #pragma unroll
    for (int i = 0; i < 64; i++) {
        int r = rh * 64 + i;
        float v = (r == c) ? ((diag == 0.f) ? 1.f : diag) : -m[i];
        if (rh == 0 && i == 0) {
            v = frv;
            if (c == 0 && v == 0.f) v = 1.f;
        }
        m[i] = v;
    }
    __syncthreads();

    for (int k = 0; k < 256; k++) {
        const int p = k & 1;
        const int kh = k >> 6, kl = k & 63;
        if (c == k) {
            #pragma unroll
            for (int i = 0; i < 64; i++) colbuf[p][rh * 64 + i] = m[i];
        }
        if (rh == kh) {
            float pv = 0.f;
            #pragma unroll
            for (int i = 0; i < 64; i++) pv = (i == kl) ? m[i] : pv;
            rowbuf[p][c] = pv;
        }
        __syncthreads();
        const float piv  = colbuf[p][k];
        const float pinv = 1.f / piv;
        const float rv   = rowbuf[p][c] * pinv;
        if (c == k) {
            #pragma unroll
            for (int i = 0; i < 64; i++) m[i] = -colbuf[p][rh * 64 + i] * pinv;
        } else {
            #pragma unroll
            for (int i = 0; i < 64; i++) m[i] -= colbuf[p][rh * 64 + i] * rv;
        }
        if (rh == kh) {
            const float dv = (c == k) ? pinv : rv;
            #pragma unroll
            for (int i = 0; i < 64; i++) m[i] = (i == kl) ? dv : m[i];
        }
    }

    #pragma unroll
    for (int i = 0; i < 64; i++)
        LLinv[(long)bz * 65536 + (long)(rh * 64 + i) * 256 + c] = __float2half(m[i]);
}

// ---------------- diag(LLinv) and d0 ----------------
__global__ void diag_d0_k(const half_t* __restrict__ LLinv, const float* __restrict__ fr,
                          float* __restrict__ diagv, float* __restrict__ d0)
{
    int i = blockIdx.x * 256 + threadIdx.x;
    if (i >= 32768) return;
    int b = i >> 8, s = i & 255;
    diagv[i] = __half2float(LLinv[(long)b * 65536 + s * 257]);
    d0[i]    = fr[i] * __half2float(LLinv[(long)b * 65536 + s * 256]);
}

// ---- a = A*(diag - LLinv^T) in place over fA, AND aT written directly (fused transpose) ----
__global__ __launch_bounds__(256)
void assemble_a(half_t* __restrict__ fA, const half_t* __restrict__ LLinv,
                const float* __restrict__ diagv, half_t* __restrict__ aT)
{
    __shared__ float  ll[32][33];
    __shared__ __half av[32][33];
    const int bz = blockIdx.z;
    const int s0 = (blockIdx.x >> 3) * 32, t0 = (blockIdx.x & 7) * 32;
    const int tid = threadIdx.x;
    const long base = (long)bz * 65536;
    #pragma unroll
    for (int it = 0; it < 4; it++) {
        int i = (tid >> 5) + it * 8, j = tid & 31;
        ll[i][j] = __half2float(LLinv[base + (long)(t0 + i) * 256 + (s0 + j)]);
    }
    __syncthreads();
    #pragma unroll
    for (int it = 0; it < 4; it++) {
        int si = (tid >> 5) + it * 8, tj = tid & 31;
        int s = s0 + si, t = t0 + tj;
        long idx = base + (long)s * 256 + t;
        float Av = __half2float(fA[idx]);
        float t1 = (t > 0) ? diagv[(bz << 8) + t] : 0.f;
        float t2 = (s > 0) ? ll[tj][si] : 0.f;
        __half hv = __float2half(Av * (t1 - t2));
        fA[idx] = hv;
        av[si][tj] = hv;
    }
    __syncthreads();
    #pragma unroll
    for (int it = 0; it < 4; it++) {
        int ti = (tid >> 5) + it * 8, sj = tid & 31;
        aT[base + (long)(t0 + ti) * 256 + (s0 + sj)] = av[sj][ti];
    }
}

// ---------------- emb = max over sequence (coalesced) ----------------
__global__ __launch_bounds__(256)
void emb_max(const float* __restrict__ outp, float* __restrict__ emb)
{
    int b = blockIdx.x;
    for (int n = threadIdx.x; n < 512; n += 256) {
        const float* p = outp + (long)b * 131072 + n;
        float mx = -3.4e38f;
        for (int t = 0; t < 256; t++) mx = fmaxf(mx, p[(long)t * 512]);
        emb[b * 512 + n] = mx;
    }
}

__global__ void diag_ws(float* out, int n, float v)
{
    int i = blockIdx.x * 256 + threadIdx.x;
    if (i < n) out[i] = v;
}

// ======================= host launch =======================
extern "C" void kernel_launch(void* const* d_in, const int* in_sizes, int n_in,
                              void* d_out, int out_size, void* d_ws, size_t ws_size,
                              hipStream_t stream)
{
    const float* x     = (const float*)d_in[0];
    const float* mask  = (const float*)d_in[1];
    const float* wihf  = (const float*)d_in[2];
    const float* whhf  = (const float*)d_in[3];
    const float* bf    = (const float*)d_in[4];
    const float* wihb  = (const float*)d_in[5];
    const float* whhb  = (const float*)d_in[6];
    const float* bb    = (const float*)d_in[7];
    const float* wtp   = (const float*)d_in[8];
    const float* btp   = (const float*)d_in[9];
    const float* wtc   = (const float*)d_in[10];
    const float* btc   = (const float*)d_in[11];
    const float* wa    = (const float*)d_in[12];
    const float* wroot = (const float*)d_in[13];
    const float* remb  = (const float*)d_in[14];
    const float* wr    = (const float*)d_in[15];
    const float* br    = (const float*)d_in[16];

    if (ws_size < 134217728ULL) {
        float enc = 100.0f + (float)((double)ws_size * 1e-9);
        diag_ws<<<dim3((out_size + 255) / 256), 256, 0, stream>>>((float*)d_out, out_size, enc);
        return;
    }

    char* ws = (char*)d_ws;
    half_t* G     = (half_t*)(ws + 0);              // 100,663,296 B per-chunk gates
    half_t* vs    = (half_t*)(ws + 100663296);      // 33,554,432 B
    half_t* tptc  = (half_t*)(ws + 0 * SEG);        // [32768][512]: tp cols 0-255, tc 256-511
    half_t* tmp   = (half_t*)(ws + 2 * SEG);
    half_t* fA    = (half_t*)(ws + 3 * SEG);
    half_t* LL    = (half_t*)(ws + 4 * SEG);
    half_t* aT    = (half_t*)(ws + 5 * SEG);
    half_t* cbuf  = (half_t*)(ws + 0 * SEG);        // over tptc (dead after fA gemm)
    half_t* pbuf  = (half_t*)(ws + 2 * SEG);        // over tmp+fA (dead after c gemm)
    half_t* wr16  = (half_t*)(ws + 4 * SEG);        // over LL (dead after assemble)

    // dead-until-final region of d_out hosts scan state + small weights
    float* ob = (float*)d_out;
    half_t*   Wp16  = (half_t*)(ob + 11000000);   // 983,040 f16
    half_t*   Whh16 = (half_t*)(ob + 11491520);   // 1,179,648 f16
    float*    bp    = ob + 12081344;
    half_t*   wtp16 = (half_t*)(ob + 12084416);   // wtp16+wtc16 contiguous [512][256] NT
    half_t*   wtc16 = (half_t*)(ob + 12117184);
    half_t*   wa16T = (half_t*)(ob + 12149952);
    float*    fr    = ob + 12182720;
    float*    d0    = ob + 12215488;
    float*    diagv = ob + 12248256;
    float*    Cst   = ob + 12281024;              // 96*256*4 f32 = 393,216 B
    half_t*   Hbuf  = (half_t*)(ob + 12379328);   // [2 p][2 d][128 b][384 hd] f16
    unsigned* flags = (unsigned*)(ob + 12500000); // 96 x 64B flag lines
    float*    bias2 = ob + 12510000;              // 512 packed bias [btp;btc]
    half_t*   vst   = (half_t*)(ob + 12648448);   // 32768 x 256 f16

    float* emb  = (float*)d_out;
    float* outp = (float*)d_out + 65536;

    // 0. init state + pack weights
    hipMemsetAsync(Hbuf, 0, 393216, stream);
    hipMemsetAsync(flags, 0, 6144, stream);
    pack_wih<<<dim3(3840), 256, 0, stream>>>(wihf, wihb, bf, bb, Wp16, bp);
    pack_whh<<<dim3(4608), 256, 0, stream>>>(whhf, whhb, Whh16);
    conv16<<<dim3(256), 256, 0, stream>>>(wtp, wtp16, 65536);
    conv16<<<dim3(256), 256, 0, stream>>>(wtc, wtc16, 65536);
    convT16<<<dim3(256), 256, 0, stream>>>(wa, wa16T, 256, 256);
    pack_bias2<<<dim3(2), 256, 0, stream>>>(btp, btc, bias2);

    // 1. chunked: G GEMM + persistent 128-step scan, twice
    for (int c = 0; c < 2; c++) {
        ggemm<<<dim3(12, 128, 2), 256, 0, stream>>>(x, Wp16, bp, G, c);
        lstm_scan<<<dim3(96), 256, 0, stream>>>(G, Whh16, Hbuf, Cst, vs, vst, flags, c);
    }

    // 2. f_r
    frow_kernel<<<dim3(8192), 256, 0, stream>>>(vst, wroot, fr);

    // 3. [tp|tc] = tanh(vst @ [wtp;wtc]^T + [btp;btc])  — ONE N=512 GEMM
    mgemm<false><<<dim3(8, 256, 1), 256, 0, stream>>>(
        vst, wtp16, tptc, M_, 512, 256, 256, 256, 512, 0, 0, 0,
        bias2, 1, nullptr, nullptr);

    // 4. tmp = tp @ w_a   (A = tp part of tptc, lda=512)
    mgemm<false><<<dim3(4, 256, 1), 256, 0, stream>>>(
        tptc, wa16T, tmp, M_, 256, 256, 512, 256, 256, 0, 0, 0,
        nullptr, 0, nullptr, nullptr);

    // 5. f = exp(tmp @ tc^T), diag zeroed (batched; B = tc part, ldb=512, sB=131072)
    mgemm<false><<<dim3(4, 2, 128), 256, 0, stream>>>(
        tmp, tptc + 256, fA, 256, 256, 256, 256, 512, 256, 65536, 131072, 65536,
        nullptr, 2, nullptr, nullptr);

    // 6-8. inverse, diag/d0, assemble (+fused aT)
    invert_gj<<<dim3(128), 1024, 0, stream>>>(fA, fr, LL);
    diag_d0_k<<<dim3(128), 256, 0, stream>>>(LL, fr, diagv, d0);
    assemble_a<<<dim3(64, 1, 128), 256, 0, stream>>>(fA, LL, diagv, aT);

    // 9. wr -> f16 (LL dead now)
    conv16<<<dim3(3072), 256, 0, stream>>>(wr, wr16, 786432);

    // 10. c = a @ vs
    mgemm<true><<<dim3(8, 2, 128), 256, 0, stream>>>(
        fA, vs, cbuf, 256, 512, 256, 256, 512, 512, 65536, 131072, 131072,
        nullptr, 0, nullptr, nullptr);

    // 11. p = aT @ vs + d0 (x) root_emb
    mgemm<true><<<dim3(8, 2, 128), 256, 0, stream>>>(
        aT, vs, pbuf, 256, 512, 256, 256, 512, 512, 65536, 131072, 131072,
        nullptr, 0, d0, remb);

    // 12. out = tanh([vs|p|c] @ wr^T + br) * mask
    mgemm_final<<<dim3(8, 256, 1), 256, 0, stream>>>(vs, pbuf, cbuf, wr16, outp, br, mask);

    // 13. emb
    emb_max<<<dim3(128), 256, 0, stream>>>(outp, emb);
}